// Round 1
// 203.094 us; speedup vs baseline: 1.1089x; 1.1089x over previous
//
#include <hip/hip_runtime.h>

// Semantics (verified through R0-R9 of previous session):
//   ABI: tokens (N,D) fp32, coords (N,2) int32, weight (D,1,3,3) fp32,
//   straight taps, straight scatter, zero padding/empty cells, bias added,
//   OUTPUT IS (D, N) flat (np advanced indexing, missing .T).
// This round (R10): identical verified math. Changes:
//   - 32 tokens per block (8 per wave, unroll-2 loop) so each thread's
//     epilogue store is a full 128B line of out[ch*N + n0..n0+31] ->
//     kills the 2x write amplification (8 blocks previously shared a line
//     across XCDs).
//   - weights/bias hoisted to registers across the 8-token loop.
#define DD 256
#define HH 384
#define WW 384
#define NTOK 65536
#define TPB 32   // tokens per block
#define TPW 8    // tokens per wave

// ---------------------------------------------------------------------------
// Prep: weight (D,9) -> wT (9,D) (straight, no flip); bias copied.
// ---------------------------------------------------------------------------
__global__ __launch_bounds__(256) void prep_kernel(
    const float* __restrict__ weight, const float* __restrict__ bias,
    float* __restrict__ wT, float* __restrict__ biasf)
{
    int ch = threadIdx.x;  // 0..255
    #pragma unroll
    for (int k = 0; k < 9; ++k)
        wT[k * DD + ch] = weight[ch * 9 + k];
    biasf[ch] = bias[ch];
}

// ---------------------------------------------------------------------------
// Scatter (straight): pos_map[r*W + c] = token index (pre-filled with -1)
// ---------------------------------------------------------------------------
__global__ __launch_bounds__(256) void scatter_pos_kernel(
    const int* __restrict__ coords, int* __restrict__ pos_map)
{
    int n = blockIdx.x * blockDim.x + threadIdx.x;
    if (n < NTOK) {
        int r = coords[2 * n + 0];
        int c = coords[2 * n + 1];
        pos_map[r * WW + c] = n;
    }
}

// ---------------------------------------------------------------------------
// Main: 4 waves/block, 8 tokens per wave (serial loop, unroll 2 for MLP);
// lane owns 4 contiguous channels -> every tap gather is a coalesced 1KB
// wave read. Epilogue: 32KB LDS transpose; thread ch stores a full 128B
// line out[ch*N + n0 .. n0+31].
// ---------------------------------------------------------------------------
__global__ __launch_bounds__(256) void conv_gather_kernel(
    const float* __restrict__ tokens,
    const int*   __restrict__ coords,
    const float* __restrict__ wT,      // (9, D)
    const float* __restrict__ biasf,   // (D,)
    const int*   __restrict__ pos_map,
    float*       __restrict__ out)     // (D, N) layout!
{
    __shared__ float s_out[TPB][DD];            // 32 KB

    const int wave = threadIdx.x >> 6;          // 0..3
    const int lane = threadIdx.x & 63;
    const int c0   = lane * 4;
    const int nw   = blockIdx.x * TPB + wave * TPW;

    const float4 bias4 = *(const float4*)(biasf + c0);
    float4 w4[9];
    #pragma unroll
    for (int k = 0; k < 9; ++k)
        w4[k] = *(const float4*)(wT + k * DD + c0);

    #pragma unroll 2
    for (int i = 0; i < TPW; ++i) {
        const int n  = nw + i;
        const int2 rc = *(const int2*)(coords + 2 * n);   // wave-uniform
        const int r = rc.x;
        const int c = rc.y;

        int   midx[9];
        float msel[9];
        #pragma unroll
        for (int dy = 0; dy < 3; ++dy) {
            #pragma unroll
            for (int dx = 0; dx < 3; ++dx) {
                const int k  = dy * 3 + dx;
                const int rr = r + dy - 1;
                const int cc = c + dx - 1;
                const bool in_bounds = (rr >= 0) && (rr < HH) && (cc >= 0) && (cc < WW);
                const int  pidx = in_bounds ? (rr * WW + cc) : 0;
                const int  m    = pos_map[pidx];
                const bool use  = in_bounds && (m >= 0);
                midx[k] = use ? m : n;              // self row is always valid
                msel[k] = use ? 1.0f : 0.0f;
            }
        }

        float4 acc = bias4;
        #pragma unroll
        for (int k = 0; k < 9; ++k) {
            const float4 t = *(const float4*)(tokens + (size_t)midx[k] * DD + c0);
            const float sel = msel[k];
            acc.x += w4[k].x * (sel * t.x);
            acc.y += w4[k].y * (sel * t.y);
            acc.z += w4[k].z * (sel * t.z);
            acc.w += w4[k].w * (sel * t.w);
        }

        *(float4*)&s_out[wave * TPW + i][c0] = acc;
    }
    __syncthreads();

    // Thread ch gathers this block's 32 consecutive tokens for channel ch
    // and stores 128B contiguous at out[ch*N + n0]. Within a wave, lanes
    // read consecutive LDS addresses (2 lanes/bank = free) and write
    // consecutive full cache lines.
    const int ch = threadIdx.x;
    float* dst = out + (size_t)ch * NTOK + blockIdx.x * TPB;
    #pragma unroll
    for (int j = 0; j < 8; ++j) {
        float4 v;
        v.x = s_out[4 * j + 0][ch];
        v.y = s_out[4 * j + 1][ch];
        v.z = s_out[4 * j + 2][ch];
        v.w = s_out[4 * j + 3][ch];
        *(float4*)(dst + 4 * j) = v;
    }
}

// ---------------------------------------------------------------------------
extern "C" void kernel_launch(void* const* d_in, const int* in_sizes, int n_in,
                              void* d_out, int out_size, void* d_ws, size_t ws_size,
                              hipStream_t stream)
{
    const float* tokens = (const float*)d_in[0];
    const int*   coords = (const int*)d_in[1];
    const float* weight = (const float*)d_in[2];
    const float* bias   = (const float*)d_in[3];
    float* out = (float*)d_out;

    // Workspace layout:
    //   [0, 9216)       wT: 9*256 fp32
    //   [9216, 10240)   biasf: 256 fp32
    //   [16384, 606208) pos_map: H*W int32
    char* ws = (char*)d_ws;
    float* wT      = (float*)ws;
    float* biasf   = (float*)(ws + 9216);
    int*   pos_map = (int*)(ws + 16384);

    hipMemsetAsync(pos_map, 0xFF, (size_t)HH * WW * sizeof(int), stream);
    prep_kernel<<<1, 256, 0, stream>>>(weight, bias, wT, biasf);
    scatter_pos_kernel<<<(NTOK + 255) / 256, 256, 0, stream>>>(coords, pos_map);
    conv_gather_kernel<<<NTOK / TPB, 256, 0, stream>>>(tokens, coords, wT, biasf,
                                                       pos_map, out);
}

// Round 2
// 174.103 us; speedup vs baseline: 1.2936x; 1.1665x over previous
//
#include <hip/hip_runtime.h>

// Semantics (verified through R0-R9 of previous session):
//   ABI: tokens (N,D) fp32, coords (N,2) int32, weight (D,1,3,3) fp32,
//   straight taps, straight scatter, zero padding/empty cells, bias added,
//   OUTPUT IS (D, N) flat (np advanced indexing, missing .T).
// R11: identical math. Latency-bound fix:
//   - coords/pos_map loads forced wave-uniform (readfirstlane) -> s_load
//     (SMEM queue, SGPR dests, no VGPR/VALU cost).
//   - phase split: all 72 pos_map scalar loads issued before any gather;
//     gather+FMA loop fully unrolled -> deep MLP instead of 2-chain overlap.
//   - invalid-tap select via sign-bit sentinel in midx (scalar ops only).
#define DD 256
#define HH 384
#define WW 384
#define NTOK 65536
#define TPB 32   // tokens per block
#define TPW 8    // tokens per wave

// ---------------------------------------------------------------------------
// Prep: weight (D,9) -> wT (9,D) (straight, no flip); bias copied.
// ---------------------------------------------------------------------------
__global__ __launch_bounds__(256) void prep_kernel(
    const float* __restrict__ weight, const float* __restrict__ bias,
    float* __restrict__ wT, float* __restrict__ biasf)
{
    int ch = threadIdx.x;  // 0..255
    #pragma unroll
    for (int k = 0; k < 9; ++k)
        wT[k * DD + ch] = weight[ch * 9 + k];
    biasf[ch] = bias[ch];
}

// ---------------------------------------------------------------------------
// Scatter (straight): pos_map[r*W + c] = token index (pre-filled with -1)
// ---------------------------------------------------------------------------
__global__ __launch_bounds__(256) void scatter_pos_kernel(
    const int* __restrict__ coords, int* __restrict__ pos_map)
{
    int n = blockIdx.x * blockDim.x + threadIdx.x;
    if (n < NTOK) {
        int r = coords[2 * n + 0];
        int c = coords[2 * n + 1];
        pos_map[r * WW + c] = n;
    }
}

// ---------------------------------------------------------------------------
// Main: 4 waves/block, 8 tokens per wave. Phase A: scalar (SMEM) loads of
// coords + all 72 pos_map entries (wave-uniform addresses). Phase B: fully
// unrolled gather+FMA, SGPR-base + lane-offset addressing. Epilogue: 32KB
// LDS transpose; thread ch stores a full 128B line out[ch*N + n0..n0+31].
// ---------------------------------------------------------------------------
__global__ __launch_bounds__(256) void conv_gather_kernel(
    const float* __restrict__ tokens,
    const int*   __restrict__ coords,
    const float* __restrict__ wT,      // (9, D)
    const float* __restrict__ biasf,   // (D,)
    const int*   __restrict__ pos_map,
    float*       __restrict__ out)     // (D, N) layout!
{
    __shared__ float s_out[TPB][DD];            // 32 KB

    const int wave = threadIdx.x >> 6;          // 0..3
    const int lane = threadIdx.x & 63;
    const int c0   = lane * 4;
    // wave-uniform first token index, forced into SGPR
    const int nw   = __builtin_amdgcn_readfirstlane(blockIdx.x * TPB + wave * TPW);

    const float4 bias4 = *(const float4*)(biasf + c0);
    float4 w4[9];
    #pragma unroll
    for (int k = 0; k < 9; ++k)
        w4[k] = *(const float4*)(wT + k * DD + c0);

    // ---- Phase A: scalar loads. All addresses wave-uniform -> s_load. ----
    // midx holds token row, or (n | sign bit) when the tap is invalid.
    int midx[TPW][9];
    #pragma unroll
    for (int i = 0; i < TPW; ++i) {
        const int n = nw + i;
        const int r = coords[2 * n + 0];        // uniform -> s_load
        const int c = coords[2 * n + 1];
        #pragma unroll
        for (int dy = 0; dy < 3; ++dy) {
            #pragma unroll
            for (int dx = 0; dx < 3; ++dx) {
                const int k  = dy * 3 + dx;
                const int rr = r + dy - 1;
                const int cc = c + dx - 1;
                const bool in_bounds = (rr >= 0) & (rr < HH) & (cc >= 0) & (cc < WW);
                const int  pidx = in_bounds ? (rr * WW + cc) : 0;
                const int  m    = pos_map[pidx];    // uniform -> s_load
                const bool use  = in_bounds & (m >= 0);
                midx[i][k] = use ? m : (n | 0x80000000);  // self row, sel=0
            }
        }
    }

    // ---- Phase B: gathers + FMA, fully unrolled for deep MLP. ----
    #pragma unroll
    for (int i = 0; i < TPW; ++i) {
        float4 acc = bias4;
        #pragma unroll
        for (int k = 0; k < 9; ++k) {
            const int   mi  = midx[i][k];
            const int   row = mi & 0x7fffffff;          // scalar
            const float sel = (mi >= 0) ? 1.0f : 0.0f;  // scalar
            const float4 t = *(const float4*)(tokens + (size_t)row * DD + c0);
            acc.x += w4[k].x * (sel * t.x);
            acc.y += w4[k].y * (sel * t.y);
            acc.z += w4[k].z * (sel * t.z);
            acc.w += w4[k].w * (sel * t.w);
        }
        *(float4*)&s_out[wave * TPW + i][c0] = acc;
    }
    __syncthreads();

    // Thread ch gathers this block's 32 consecutive tokens for channel ch
    // and stores 128B contiguous at out[ch*N + n0]. LDS reads are 2-way
    // bank aliased (free); stores give one full 128B line per thread.
    const int ch = threadIdx.x;
    float* dst = out + (size_t)ch * NTOK + blockIdx.x * TPB;
    #pragma unroll
    for (int j = 0; j < 8; ++j) {
        float4 v;
        v.x = s_out[4 * j + 0][ch];
        v.y = s_out[4 * j + 1][ch];
        v.z = s_out[4 * j + 2][ch];
        v.w = s_out[4 * j + 3][ch];
        *(float4*)(dst + 4 * j) = v;
    }
}

// ---------------------------------------------------------------------------
extern "C" void kernel_launch(void* const* d_in, const int* in_sizes, int n_in,
                              void* d_out, int out_size, void* d_ws, size_t ws_size,
                              hipStream_t stream)
{
    const float* tokens = (const float*)d_in[0];
    const int*   coords = (const int*)d_in[1];
    const float* weight = (const float*)d_in[2];
    const float* bias   = (const float*)d_in[3];
    float* out = (float*)d_out;

    // Workspace layout:
    //   [0, 9216)       wT: 9*256 fp32
    //   [9216, 10240)   biasf: 256 fp32
    //   [16384, 606208) pos_map: H*W int32
    char* ws = (char*)d_ws;
    float* wT      = (float*)ws;
    float* biasf   = (float*)(ws + 9216);
    int*   pos_map = (int*)(ws + 16384);

    hipMemsetAsync(pos_map, 0xFF, (size_t)HH * WW * sizeof(int), stream);
    prep_kernel<<<1, 256, 0, stream>>>(weight, bias, wT, biasf);
    scatter_pos_kernel<<<(NTOK + 255) / 256, 256, 0, stream>>>(coords, pos_map);
    conv_gather_kernel<<<NTOK / TPB, 256, 0, stream>>>(tokens, coords, wT, biasf,
                                                       pos_map, out);
}